// Round 6
// baseline (283.258 us; speedup 1.0000x reference)
//
#include <hip/hip_runtime.h>
#include <math.h>

#define CB 512
#define CS 1024
#define CT 50
#define PF 4   // x-prefetch depth / renorm cadence

typedef float v2f __attribute__((ext_vector_type(2)));

__global__ void zero_out_kernel(float* out) { out[0] = 0.0f; }

__device__ __forceinline__ int lane0_bits(float v) {
    return __builtin_amdgcn_readlane(__float_as_int(v), 0);
}

// quad_perm DPP move (VALU pipe, no DS): ctrl 0xB1 = xor1, 0x4E = xor2
template <int CTRL>
__device__ __forceinline__ float qperm(float v) {
    return __int_as_float(__builtin_amdgcn_update_dpp(
        0, __float_as_int(v), CTRL, 0xf, 0xf, false));
}

__global__ __launch_bounds__(128, 1) void crf_scan_kernel(
    const float* __restrict__ scores,    // (B,S,T)
    const int*   __restrict__ tags,      // (B,S)
    const int*   __restrict__ mask,      // (B,S)
    const float* __restrict__ trans,     // (T,T)
    const float* __restrict__ start_tr,  // (T)
    const float* __restrict__ end_tr,    // (T)
    float* __restrict__ out)             // scalar
{
    const int b    = blockIdx.x;
    const int tid  = threadIdx.x;
    const int w    = tid >> 6;           // wave 0 = forward, wave 1 = backward
    const int lane = tid & 63;
    const int xl   = (lane < CT) ? lane : 0;
    const int g    = lane & 3;           // i-quarter this lane accumulates
    const int m    = lane >> 2;          // quad index; lane owns state == lane
    const bool selb0 = (lane & 1) != 0;
    const bool selb1 = (lane & 2) != 0;

    __shared__ __attribute__((aligned(16))) float sTrans[CT * CT];
    __shared__ __attribute__((aligned(16))) float sA[64];
    __shared__ __attribute__((aligned(16))) float sB[64];
    __shared__ float sLZ[2], sN[2];

    for (int k = tid; k < CT * CT; k += 128) sTrans[k] = trans[k];
    __syncthreads();

    // E fragments: lane covers i in [16g, 16g+16), states s = 4m+c, c<4.
    // fwd (w=0): coeff(i,s) = exp(trans[i][s]); bwd (w=1): coeff(i,s) = exp(trans[s][i]).
    // Pads (i>=50 or s>=50) are exactly 0 so pad states stay 0 forever.
    v2f EC0[16], EC1[16];
    {
        const int i0 = 16 * g, s0 = 4 * m;
        #pragma unroll
        for (int k = 0; k < 16; ++k) {
            const int i = i0 + k;
            float e[4] = {0.f, 0.f, 0.f, 0.f};
            if (i < CT) {
                #pragma unroll
                for (int c = 0; c < 4; ++c) {
                    const int s = s0 + c;
                    if (s < CT)
                        e[c] = __expf(w == 0 ? sTrans[i * CT + s]
                                             : sTrans[s * CT + i]);
                }
            }
            EC0[k] = (v2f){e[0], e[1]};
            EC1[k] = (v2f){e[2], e[3]};
        }
    }

    // bpermute pull addresses: lane pulls source lanes 16g+k, k=0..15
    int bpa[16];
    #pragma unroll
    for (int k = 0; k < 16; ++k) bpa[k] = (16 * g + k) << 2;

    // sequence length (prefix mask)
    const int* mrow = mask + (size_t)b * CS;
    int len = 0;
    for (int t = lane; t < CS; t += 64) len += mrow[t];
    #pragma unroll
    for (int off = 32; off; off >>= 1) len += __shfl_xor(len, off);

    const float* srow = scores + (size_t)b * CS * CT;
    const float* sx   = srow + xl;

    const int tm    = (len - 1) >> 1;
    const int count = (w == 0) ? tm : ((len >= 2) ? (len - 2 - tm) : 0);
    const int base  = (w == 0) ? 1 : (len - 2);
    const int dir   = (w == 0) ? 1 : -1;

    // linear-domain state; pad lanes (state>=50) exactly 0
    float st;
    if (w == 0) {
        st = (lane < CT) ? __expf(start_tr[lane] + sx[0]) : 0.f;
    } else {
        st = (lane < CT)
            ? ((len >= 2) ? __expf(end_tr[lane] + sx[(size_t)(len - 1) * CT])
                          : __expf(end_tr[lane]))
            : 0.f;
    }
    int   kexp = 0;
    float rsc  = 1.0f;

    // One step: single-phase all-gather via 16 ds_bpermute pulls (register
    // crossbar — no LDS memory, no write leg, no fences), consumed IN ISSUE
    // ORDER by the 16-deep FMA chain (overlaps pull latency), quad_perm DPP
    // combine, select own state, scale by EX (renorm pre-folded).
    #define STEP(EX)                                                        \
    {                                                                       \
        const int sti = __float_as_int(st);                                 \
        int pi[16];                                                         \
        _Pragma("unroll")                                                   \
        for (int kk = 0; kk < 16; ++kk)                                     \
            pi[kk] = __builtin_amdgcn_ds_bpermute(bpa[kk], sti);            \
        v2f a0 = {0.f,0.f}, a1 = {0.f,0.f};                                 \
        _Pragma("unroll")                                                   \
        for (int kk = 0; kk < 16; ++kk) {                                   \
            const float pv = __int_as_float(pi[kk]);                        \
            const v2f t2 = {pv, pv};                                        \
            a0 = __builtin_elementwise_fma(t2, EC0[kk], a0);                \
            a1 = __builtin_elementwise_fma(t2, EC1[kk], a1);                \
        }                                                                   \
        a0.x += qperm<0xB1>(a0.x); a0.y += qperm<0xB1>(a0.y);               \
        a1.x += qperm<0xB1>(a1.x); a1.y += qperm<0xB1>(a1.y);               \
        a0.x += qperm<0x4E>(a0.x); a0.y += qperm<0x4E>(a0.y);               \
        a1.x += qperm<0x4E>(a1.x); a1.y += qperm<0x4E>(a1.y);               \
        const float o01 = selb0 ? a0.y : a0.x;                              \
        const float o23 = selb0 ? a1.y : a1.x;                              \
        st = (selb1 ? o23 : o01) * (EX);                                    \
    }

    // Renorm: read lane0 exponent of st (parallel to the gather; does NOT
    // touch st). Scale 2^(127-e) is applied through the next step's EX
    // (linear, power-of-2 exact).
    #define RENORM()                                                        \
    {                                                                       \
        int sb = lane0_bits(st);                                            \
        int e  = (sb >> 23) & 0xff;                                         \
        kexp  += e - 127;                                                   \
        rsc    = __int_as_float((254 - e) << 23);                           \
    }

    // ---- scan: PF-step chunks, x prefetch, renorm folded into EX ----
    float xpf[PF];
    #pragma unroll
    for (int k = 0; k < PF; ++k) {
        int idx = base + dir * k;
        if (idx < 0) idx = 0;
        xpf[k] = sx[(size_t)idx * CT];
    }
    int k = 0;
    while (k + PF <= count) {
        float exk[PF];
        #pragma unroll
        for (int j = 0; j < PF; ++j) exk[j] = __expf(xpf[j]);
        #pragma unroll
        for (int j = 0; j < PF; ++j) {
            int idx = base + dir * (k + PF + j);
            if (idx < 0) idx = 0;
            xpf[j] = sx[(size_t)idx * CT];
        }
        RENORM();
        STEP(exk[0] * rsc);
        STEP(exk[1]);
        STEP(exk[2]);
        STEP(exk[3]);
        k += PF;
    }
    {
        const int rem = count - k;   // 0..PF-1
        if (rem >= 1) { float e = __expf(xpf[0]); RENORM(); STEP(e * rsc); }
        if (rem >= 2) { float e = __expf(xpf[1]); RENORM(); STEP(e * rsc); }
        if (rem >= 3) { float e = __expf(xpf[2]); RENORM(); STEP(e * rsc); }
        // bwd epilogue: B_tm = E * C_{tm+1} (no exp(x) factor)
        if (w == 1 && len >= 2) { RENORM(); STEP(rsc); }
    }
    RENORM();
    st *= rsc;
    #undef STEP
    #undef RENORM

    // ---- combine across waves ----
    if (w == 0) sA[lane] = (lane < CT) ? st : 0.0f;
    else        sB[lane] = (lane < CT) ? st : 0.0f;
    if (lane == 0) sLZ[w] = (float)kexp * 0.6931471805599453f;
    __syncthreads();

    // numerator: gold-path score, all 128 threads
    const int* trow = tags + (size_t)b * CS;
    float nsum = 0.0f;
    for (int t = tid; t < CS; t += 128) {
        if (t < len) {
            int tg = trow[t];
            nsum += srow[(size_t)t * CT + tg];
            if (t >= 1) nsum += sTrans[trow[t - 1] * CT + tg];
        }
    }
    #pragma unroll
    for (int off = 32; off; off >>= 1) nsum += __shfl_xor(nsum, off);
    if (lane == 0) sN[w] = nsum;

    float den = 0.0f;
    if (w == 0) {
        float vp = sA[lane] * sB[lane];
        #pragma unroll
        for (int off = 32; off; off >>= 1) vp += __shfl_xor(vp, off);
        den = sLZ[0] + sLZ[1] + __logf(vp);
    }
    __syncthreads();

    if (tid == 0) {
        float num = sN[0] + sN[1] + start_tr[trow[0]] + end_tr[trow[len - 1]];
        atomicAdd(out, (den - num) * (1.0f / CB));
    }
}

extern "C" void kernel_launch(void* const* d_in, const int* in_sizes, int n_in,
                              void* d_out, int out_size, void* d_ws, size_t ws_size,
                              hipStream_t stream) {
    const float* scores   = (const float*)d_in[0];
    const int*   tags     = (const int*)d_in[1];
    const int*   mask     = (const int*)d_in[2];
    const float* trans    = (const float*)d_in[3];
    const float* start_tr = (const float*)d_in[4];
    const float* end_tr   = (const float*)d_in[5];
    float* out = (float*)d_out;

    zero_out_kernel<<<1, 1, 0, stream>>>(out);
    crf_scan_kernel<<<CB, 128, 0, stream>>>(scores, tags, mask, trans,
                                            start_tr, end_tr, out);
}

// Round 7
// 268.382 us; speedup vs baseline: 1.0554x; 1.0554x over previous
//
#include <hip/hip_runtime.h>
#include <math.h>

#define CB 512
#define CS 1024
#define CT 50
#define PF 4   // x-prefetch depth / renorm cadence

typedef float v2f __attribute__((ext_vector_type(2)));

__global__ void zero_out_kernel(float* out) { out[0] = 0.0f; }

// Compiler-level fence only — same-wave DS ops complete in order on CDNA.
__device__ __forceinline__ void wave_fence() {
    __builtin_amdgcn_wave_barrier();
    asm volatile("" ::: "memory");
}

__device__ __forceinline__ int lane0_bits(float v) {
    return __builtin_amdgcn_readlane(__float_as_int(v), 0);
}

// quad_perm DPP move (VALU pipe, no DS): ctrl 0xB1 = xor1, 0x4E = xor2
template <int CTRL>
__device__ __forceinline__ float qperm(float v) {
    return __int_as_float(__builtin_amdgcn_update_dpp(
        0, __float_as_int(v), CTRL, 0xf, 0xf, false));
}

__global__ __launch_bounds__(128, 1) void crf_scan_kernel(
    const float* __restrict__ scores,    // (B,S,T)
    const int*   __restrict__ tags,      // (B,S)
    const int*   __restrict__ mask,      // (B,S)
    const float* __restrict__ trans,     // (T,T)
    const float* __restrict__ start_tr,  // (T)
    const float* __restrict__ end_tr,    // (T)
    float* __restrict__ out)             // scalar
{
    const int b    = blockIdx.x;
    const int tid  = threadIdx.x;
    const int w    = tid >> 6;           // wave 0 = forward, wave 1 = backward
    const int lane = tid & 63;
    const int xl   = (lane < CT) ? lane : 0;
    const int g    = lane & 3;           // i-quarter this lane accumulates
    const int m    = lane >> 2;          // quad index; lane owns state == lane
    const bool selb0 = (lane & 1) != 0;
    const bool selb1 = (lane & 2) != 0;

    __shared__ __attribute__((aligned(16))) float sTrans[CT * CT];
    __shared__ __attribute__((aligned(16))) float sP2[2][2][64]; // [wave][buf][state]
    __shared__ __attribute__((aligned(16))) float sA[64];
    __shared__ __attribute__((aligned(16))) float sB[64];
    __shared__ float sLZ[2], sN[2];

    for (int k = tid; k < CT * CT; k += 128) sTrans[k] = trans[k];
    __syncthreads();

    // E fragments: lane covers i in [16g, 16g+16), states s = 4m+c, c<4.
    // fwd (w=0): coeff(i,s) = exp(trans[i][s]); bwd (w=1): coeff(i,s) = exp(trans[s][i]).
    // Pads (i>=50 or s>=50) are exactly 0 so pad states stay 0 forever.
    v2f EC0[16], EC1[16];
    {
        const int i0 = 16 * g, s0 = 4 * m;
        #pragma unroll
        for (int k = 0; k < 16; ++k) {
            const int i = i0 + k;
            float e[4] = {0.f, 0.f, 0.f, 0.f};
            if (i < CT) {
                #pragma unroll
                for (int c = 0; c < 4; ++c) {
                    const int s = s0 + c;
                    if (s < CT)
                        e[c] = __expf(w == 0 ? sTrans[i * CT + s]
                                             : sTrans[s * CT + i]);
                }
            }
            EC0[k] = (v2f){e[0], e[1]};
            EC1[k] = (v2f){e[2], e[3]};
        }
    }

    // sequence length (prefix mask)
    const int* mrow = mask + (size_t)b * CS;
    int len = 0;
    for (int t = lane; t < CS; t += 64) len += mrow[t];
    #pragma unroll
    for (int off = 32; off; off >>= 1) len += __shfl_xor(len, off);

    const float* srow = scores + (size_t)b * CS * CT;
    const float* sx   = srow + xl;

    const int tm    = (len - 1) >> 1;
    const int count = (w == 0) ? tm : ((len >= 2) ? (len - 2 - tm) : 0);
    const int base  = (w == 0) ? 1 : (len - 2);
    const int dir   = (w == 0) ? 1 : -1;

    // linear-domain state; pad lanes (state>=50) exactly 0
    float st;
    if (w == 0) {
        st = (lane < CT) ? __expf(start_tr[lane] + sx[0]) : 0.f;
    } else {
        st = (lane < CT)
            ? ((len >= 2) ? __expf(end_tr[lane] + sx[(size_t)(len - 1) * CT])
                          : __expf(end_tr[lane]))
            : 0.f;
    }
    int   kexp = 0;
    float rsc  = 1.0f;

    // double-buffered broadcast slots (per wave)
    float*        wbuf0 = &sP2[w][0][lane];
    float*        wbuf1 = &sP2[w][1][lane];
    const float4* rbuf0 = (const float4*)&sP2[w][0][16 * g];
    const float4* rbuf1 = (const float4*)&sP2[w][1][16 * g];

    #define T2(V) ((v2f){(V), (V)})
    #define MACF(B, C, V, K)                                                \
        B = __builtin_elementwise_fma(T2(V), EC0[K], B);                    \
        C = __builtin_elementwise_fma(T2(V), EC1[K], C);

    // One step: broadcast state via LDS (1 write + 4 b128 reads, double-
    // buffered), FOUR independent mul+3-fma sub-chains — sub-chain k consumes
    // ONLY p_k, so it starts as that b128 lands (read-order overlap preserved,
    // arithmetic depth 4+2 instead of 16) — 2-level merge, quad_perm DPP
    // combine, select own state, scale by EX (renorm pre-folded).
    #define STEP(WPTR, RPTR, EX)                                            \
    {                                                                       \
        *(WPTR) = st;                                                       \
        wave_fence();                                                       \
        const float4 p0 = (RPTR)[0];                                        \
        const float4 p1 = (RPTR)[1];                                        \
        const float4 p2 = (RPTR)[2];                                        \
        const float4 p3 = (RPTR)[3];                                        \
        wave_fence(); /* WAR: reads ordered before this buffer's reuse */   \
        v2f b0 = T2(p0.x) * EC0[0],  c0 = T2(p0.x) * EC1[0];                \
        MACF(b0, c0, p0.y, 1)  MACF(b0, c0, p0.z, 2)  MACF(b0, c0, p0.w, 3) \
        v2f b1 = T2(p1.x) * EC0[4],  c1 = T2(p1.x) * EC1[4];                \
        MACF(b1, c1, p1.y, 5)  MACF(b1, c1, p1.z, 6)  MACF(b1, c1, p1.w, 7) \
        v2f b2 = T2(p2.x) * EC0[8],  c2 = T2(p2.x) * EC1[8];                \
        MACF(b2, c2, p2.y, 9)  MACF(b2, c2, p2.z, 10) MACF(b2, c2, p2.w, 11)\
        v2f b3 = T2(p3.x) * EC0[12], c3 = T2(p3.x) * EC1[12];               \
        MACF(b3, c3, p3.y, 13) MACF(b3, c3, p3.z, 14) MACF(b3, c3, p3.w, 15)\
        v2f a0 = (b0 + b1) + (b2 + b3);                                     \
        v2f a1 = (c0 + c1) + (c2 + c3);                                     \
        a0.x += qperm<0xB1>(a0.x); a0.y += qperm<0xB1>(a0.y);               \
        a1.x += qperm<0xB1>(a1.x); a1.y += qperm<0xB1>(a1.y);               \
        a0.x += qperm<0x4E>(a0.x); a0.y += qperm<0x4E>(a0.y);               \
        a1.x += qperm<0x4E>(a1.x); a1.y += qperm<0x4E>(a1.y);               \
        const float o01 = selb0 ? a0.y : a0.x;                              \
        const float o23 = selb0 ? a1.y : a1.x;                              \
        st = (selb1 ? o23 : o01) * (EX);                                    \
    }

    // Renorm: read lane0 exponent of st (parallel to the broadcast; does NOT
    // touch st, so the ds_write launches immediately). Scale 2^(127-e) is
    // applied through the next step's EX (linear, power-of-2 exact).
    #define RENORM()                                                        \
    {                                                                       \
        int sb = lane0_bits(st);                                            \
        int e  = (sb >> 23) & 0xff;                                         \
        kexp  += e - 127;                                                   \
        rsc    = __int_as_float((254 - e) << 23);                           \
    }

    // ---- scan: PF-step chunks, x prefetch, renorm folded into EX ----
    float xpf[PF];
    #pragma unroll
    for (int k = 0; k < PF; ++k) {
        int idx = base + dir * k;
        if (idx < 0) idx = 0;
        xpf[k] = sx[(size_t)idx * CT];
    }
    int k = 0;
    while (k + PF <= count) {
        float exk[PF];
        #pragma unroll
        for (int j = 0; j < PF; ++j) exk[j] = __expf(xpf[j]);
        #pragma unroll
        for (int j = 0; j < PF; ++j) {
            int idx = base + dir * (k + PF + j);
            if (idx < 0) idx = 0;
            xpf[j] = sx[(size_t)idx * CT];
        }
        RENORM();
        STEP(wbuf0, rbuf0, exk[0] * rsc);
        STEP(wbuf1, rbuf1, exk[1]);
        STEP(wbuf0, rbuf0, exk[2]);
        STEP(wbuf1, rbuf1, exk[3]);
        k += PF;
    }
    {
        const int rem = count - k;   // 0..PF-1
        if (rem >= 1) { float e = __expf(xpf[0]); RENORM(); STEP(wbuf0, rbuf0, e * rsc); }
        if (rem >= 2) { float e = __expf(xpf[1]); RENORM(); STEP(wbuf1, rbuf1, e * rsc); }
        if (rem >= 3) { float e = __expf(xpf[2]); RENORM(); STEP(wbuf0, rbuf0, e * rsc); }
        // bwd epilogue: B_tm = E * C_{tm+1} (no exp(x) factor)
        if (w == 1 && len >= 2) {
            RENORM();
            if (rem & 1) { STEP(wbuf1, rbuf1, rsc); }
            else         { STEP(wbuf0, rbuf0, rsc); }
        }
    }
    RENORM();
    st *= rsc;
    #undef STEP
    #undef RENORM
    #undef MACF
    #undef T2

    // ---- combine across waves ----
    if (w == 0) sA[lane] = (lane < CT) ? st : 0.0f;
    else        sB[lane] = (lane < CT) ? st : 0.0f;
    if (lane == 0) sLZ[w] = (float)kexp * 0.6931471805599453f;
    __syncthreads();

    // numerator: gold-path score, all 128 threads
    const int* trow = tags + (size_t)b * CS;
    float nsum = 0.0f;
    for (int t = tid; t < CS; t += 128) {
        if (t < len) {
            int tg = trow[t];
            nsum += srow[(size_t)t * CT + tg];
            if (t >= 1) nsum += sTrans[trow[t - 1] * CT + tg];
        }
    }
    #pragma unroll
    for (int off = 32; off; off >>= 1) nsum += __shfl_xor(nsum, off);
    if (lane == 0) sN[w] = nsum;

    float den = 0.0f;
    if (w == 0) {
        float vp = sA[lane] * sB[lane];
        #pragma unroll
        for (int off = 32; off; off >>= 1) vp += __shfl_xor(vp, off);
        den = sLZ[0] + sLZ[1] + __logf(vp);
    }
    __syncthreads();

    if (tid == 0) {
        float num = sN[0] + sN[1] + start_tr[trow[0]] + end_tr[trow[len - 1]];
        atomicAdd(out, (den - num) * (1.0f / CB));
    }
}

extern "C" void kernel_launch(void* const* d_in, const int* in_sizes, int n_in,
                              void* d_out, int out_size, void* d_ws, size_t ws_size,
                              hipStream_t stream) {
    const float* scores   = (const float*)d_in[0];
    const int*   tags     = (const int*)d_in[1];
    const int*   mask     = (const int*)d_in[2];
    const float* trans    = (const float*)d_in[3];
    const float* start_tr = (const float*)d_in[4];
    const float* end_tr   = (const float*)d_in[5];
    float* out = (float*)d_out;

    zero_out_kernel<<<1, 1, 0, stream>>>(out);
    crf_scan_kernel<<<CB, 128, 0, stream>>>(scores, tags, mask, trans,
                                            start_tr, end_tr, out);
}

// Round 8
// 259.554 us; speedup vs baseline: 1.0913x; 1.0340x over previous
//
#include <hip/hip_runtime.h>
#include <math.h>

#define CB 512
#define CS 1024
#define CT 50
#define PF 4   // x-prefetch depth / renorm cadence

typedef float v2f __attribute__((ext_vector_type(2)));

__global__ void zero_out_kernel(float* out) { out[0] = 0.0f; }

// Compiler-level fence only — same-wave DS ops complete in order on CDNA.
__device__ __forceinline__ void wave_fence() {
    __builtin_amdgcn_wave_barrier();
    asm volatile("" ::: "memory");
}

__device__ __forceinline__ int lane0_bits(float v) {
    return __builtin_amdgcn_readlane(__float_as_int(v), 0);
}

// quad_perm DPP move (VALU pipe, no DS): ctrl 0xB1 = xor1, 0x4E = xor2
template <int CTRL>
__device__ __forceinline__ float qperm(float v) {
    return __int_as_float(__builtin_amdgcn_update_dpp(
        0, __float_as_int(v), CTRL, 0xf, 0xf, false));
}

__global__ __launch_bounds__(128, 1) void crf_scan_kernel(
    const float* __restrict__ scores,    // (B,S,T)
    const int*   __restrict__ tags,      // (B,S)
    const int*   __restrict__ mask,      // (B,S)
    const float* __restrict__ trans,     // (T,T)
    const float* __restrict__ start_tr,  // (T)
    const float* __restrict__ end_tr,    // (T)
    float* __restrict__ out)             // scalar
{
    const int b    = blockIdx.x;
    const int tid  = threadIdx.x;
    const int w    = tid >> 6;           // wave 0 = forward, wave 1 = backward
    const int lane = tid & 63;
    const int xl   = (lane < CT) ? lane : 0;
    const int g    = lane & 3;           // i-quarter this lane accumulates
    const int m    = lane >> 2;          // quad index; lane owns state == lane
    const bool selb0 = (lane & 1) != 0;
    const bool selb1 = (lane & 2) != 0;

    __shared__ __attribute__((aligned(16))) float sTrans[CT * CT];
    __shared__ __attribute__((aligned(16))) float sP2[2][2][64]; // [wave][buf][state]
    __shared__ __attribute__((aligned(16))) float sA[64];
    __shared__ __attribute__((aligned(16))) float sB[64];
    __shared__ float sLZ[2], sN[2];

    for (int k = tid; k < CT * CT; k += 128) sTrans[k] = trans[k];
    __syncthreads();

    // E fragments: lane covers i in [16g, 16g+16), states s = 4m+c, c<4.
    // fwd (w=0): coeff(i,s) = exp(trans[i][s]); bwd (w=1): coeff(i,s) = exp(trans[s][i]).
    // Pads (i>=50 or s>=50) are exactly 0 so pad states stay 0 forever.
    v2f EC0[16], EC1[16];
    {
        const int i0 = 16 * g, s0 = 4 * m;
        #pragma unroll
        for (int k = 0; k < 16; ++k) {
            const int i = i0 + k;
            float e[4] = {0.f, 0.f, 0.f, 0.f};
            if (i < CT) {
                #pragma unroll
                for (int c = 0; c < 4; ++c) {
                    const int s = s0 + c;
                    if (s < CT)
                        e[c] = __expf(w == 0 ? sTrans[i * CT + s]
                                             : sTrans[s * CT + i]);
                }
            }
            EC0[k] = (v2f){e[0], e[1]};
            EC1[k] = (v2f){e[2], e[3]};
        }
    }

    // sequence length (prefix mask)
    const int* mrow = mask + (size_t)b * CS;
    int len = 0;
    for (int t = lane; t < CS; t += 64) len += mrow[t];
    #pragma unroll
    for (int off = 32; off; off >>= 1) len += __shfl_xor(len, off);

    const float* srow = scores + (size_t)b * CS * CT;
    const float* sx   = srow + xl;

    const int tm    = (len - 1) >> 1;
    const int count = (w == 0) ? tm : ((len >= 2) ? (len - 2 - tm) : 0);
    const int base  = (w == 0) ? 1 : (len - 2);
    const int dir   = (w == 0) ? 1 : -1;

    // linear-domain state; pad lanes (state>=50) exactly 0
    float st;
    if (w == 0) {
        st = (lane < CT) ? __expf(start_tr[lane] + sx[0]) : 0.f;
    } else {
        st = (lane < CT)
            ? ((len >= 2) ? __expf(end_tr[lane] + sx[(size_t)(len - 1) * CT])
                          : __expf(end_tr[lane]))
            : 0.f;
    }
    int   kexp = 0;
    float rsc  = 1.0f;

    // double-buffered broadcast slots (per wave)
    float*        wbuf0 = &sP2[w][0][lane];
    float*        wbuf1 = &sP2[w][1][lane];
    const float4* rbuf0 = (const float4*)&sP2[w][0][16 * g];
    const float4* rbuf1 = (const float4*)&sP2[w][1][16 * g];

    // One step: broadcast state via LDS (1 write + 4 b128 reads, double-buffered),
    // 16-deep IN-READ-ORDER FMA chain (hides read latency under lgkmcnt staging),
    // quad_perm DPP combine, select own state, scale by EX (renorm pre-folded).
    #define STEP(WPTR, RPTR, EX)                                            \
    {                                                                       \
        *(WPTR) = st;                                                       \
        wave_fence();                                                       \
        const float4 p0 = (RPTR)[0];                                        \
        const float4 p1 = (RPTR)[1];                                        \
        const float4 p2 = (RPTR)[2];                                        \
        const float4 p3 = (RPTR)[3];                                        \
        wave_fence(); /* WAR: reads ordered before this buffer's reuse */   \
        float pv[16] = {p0.x,p0.y,p0.z,p0.w, p1.x,p1.y,p1.z,p1.w,           \
                        p2.x,p2.y,p2.z,p2.w, p3.x,p3.y,p3.z,p3.w};          \
        v2f a0 = {0.f,0.f}, a1 = {0.f,0.f};                                 \
        _Pragma("unroll")                                                   \
        for (int kk = 0; kk < 16; ++kk) {                                   \
            const v2f t2 = {pv[kk], pv[kk]};                                \
            a0 = __builtin_elementwise_fma(t2, EC0[kk], a0);                \
            a1 = __builtin_elementwise_fma(t2, EC1[kk], a1);                \
        }                                                                   \
        a0.x += qperm<0xB1>(a0.x); a0.y += qperm<0xB1>(a0.y);               \
        a1.x += qperm<0xB1>(a1.x); a1.y += qperm<0xB1>(a1.y);               \
        a0.x += qperm<0x4E>(a0.x); a0.y += qperm<0x4E>(a0.y);               \
        a1.x += qperm<0x4E>(a1.x); a1.y += qperm<0x4E>(a1.y);               \
        const float o01 = selb0 ? a0.y : a0.x;                              \
        const float o23 = selb0 ? a1.y : a1.x;                              \
        st = (selb1 ? o23 : o01) * (EX);                                    \
    }

    // Renorm: read lane0 exponent of st (parallel to the broadcast; does NOT
    // touch st, so the ds_write launches immediately). Scale 2^(127-e) is
    // applied through the next step's EX (linear, power-of-2 exact).
    #define RENORM()                                                        \
    {                                                                       \
        int sb = lane0_bits(st);                                            \
        int e  = (sb >> 23) & 0xff;                                         \
        kexp  += e - 127;                                                   \
        rsc    = __int_as_float((254 - e) << 23);                           \
    }

    // ---- scan: PF-step chunks, x prefetch, renorm folded into EX ----
    float xpf[PF];
    #pragma unroll
    for (int k = 0; k < PF; ++k) {
        int idx = base + dir * k;
        if (idx < 0) idx = 0;
        xpf[k] = sx[(size_t)idx * CT];
    }
    int k = 0;
    while (k + PF <= count) {
        float exk[PF];
        #pragma unroll
        for (int j = 0; j < PF; ++j) exk[j] = __expf(xpf[j]);
        #pragma unroll
        for (int j = 0; j < PF; ++j) {
            int idx = base + dir * (k + PF + j);
            if (idx < 0) idx = 0;
            xpf[j] = sx[(size_t)idx * CT];
        }
        RENORM();
        STEP(wbuf0, rbuf0, exk[0] * rsc);
        STEP(wbuf1, rbuf1, exk[1]);
        STEP(wbuf0, rbuf0, exk[2]);
        STEP(wbuf1, rbuf1, exk[3]);
        k += PF;
    }
    {
        const int rem = count - k;   // 0..PF-1
        if (rem >= 1) { float e = __expf(xpf[0]); RENORM(); STEP(wbuf0, rbuf0, e * rsc); }
        if (rem >= 2) { float e = __expf(xpf[1]); RENORM(); STEP(wbuf1, rbuf1, e * rsc); }
        if (rem >= 3) { float e = __expf(xpf[2]); RENORM(); STEP(wbuf0, rbuf0, e * rsc); }
        // bwd epilogue: B_tm = E * C_{tm+1} (no exp(x) factor)
        if (w == 1 && len >= 2) {
            RENORM();
            if (rem & 1) { STEP(wbuf1, rbuf1, rsc); }
            else         { STEP(wbuf0, rbuf0, rsc); }
        }
    }
    RENORM();
    st *= rsc;
    #undef STEP
    #undef RENORM

    // ---- combine across waves ----
    if (w == 0) sA[lane] = (lane < CT) ? st : 0.0f;
    else        sB[lane] = (lane < CT) ? st : 0.0f;
    if (lane == 0) sLZ[w] = (float)kexp * 0.6931471805599453f;
    __syncthreads();

    // numerator: gold-path score, all 128 threads
    const int* trow = tags + (size_t)b * CS;
    float nsum = 0.0f;
    for (int t = tid; t < CS; t += 128) {
        if (t < len) {
            int tg = trow[t];
            nsum += srow[(size_t)t * CT + tg];
            if (t >= 1) nsum += sTrans[trow[t - 1] * CT + tg];
        }
    }
    #pragma unroll
    for (int off = 32; off; off >>= 1) nsum += __shfl_xor(nsum, off);
    if (lane == 0) sN[w] = nsum;

    float den = 0.0f;
    if (w == 0) {
        float vp = sA[lane] * sB[lane];
        #pragma unroll
        for (int off = 32; off; off >>= 1) vp += __shfl_xor(vp, off);
        den = sLZ[0] + sLZ[1] + __logf(vp);
    }
    __syncthreads();

    if (tid == 0) {
        float num = sN[0] + sN[1] + start_tr[trow[0]] + end_tr[trow[len - 1]];
        atomicAdd(out, (den - num) * (1.0f / CB));
    }
}

extern "C" void kernel_launch(void* const* d_in, const int* in_sizes, int n_in,
                              void* d_out, int out_size, void* d_ws, size_t ws_size,
                              hipStream_t stream) {
    const float* scores   = (const float*)d_in[0];
    const int*   tags     = (const int*)d_in[1];
    const int*   mask     = (const int*)d_in[2];
    const float* trans    = (const float*)d_in[3];
    const float* start_tr = (const float*)d_in[4];
    const float* end_tr   = (const float*)d_in[5];
    float* out = (float*)d_out;

    zero_out_kernel<<<1, 1, 0, stream>>>(out);
    crf_scan_kernel<<<CB, 128, 0, stream>>>(scores, tags, mask, trans,
                                            start_tr, end_tr, out);
}